// Round 5
// baseline (234.428 us; speedup 1.0000x reference)
//
#include <hip/hip_runtime.h>
#include <hip/hip_bf16.h>

#define NN 100000   // nodes
#define NE 800000   // edges
#define NF 500      // in features
#define NH 64       // hidden
#define NC 16       // classes
#define SCAN_B 98   // 98 * 1024 >= NN
#define G1HALF 391
#define ROLEB 224   // extra hist/scatter blocks fused into gemm1 halves

typedef __attribute__((ext_vector_type(4))) float f32x4;
typedef __attribute__((ext_vector_type(8))) short bf16x8;  // 8 bf16 (4 VGPRs)

// packed fp32x2 -> bf16x2 (compiler emits v_cvt_pk_bf16_f32, RNE)
__device__ __forceinline__ unsigned int pkbf(float a, float b) {
    union { __hip_bfloat162 h; unsigned int u; } v;
    v.h = __float22bfloat162_rn(make_float2(a, b));
    return v.u;
}
__device__ __forceinline__ unsigned short bf1(float a) {
    union { __hip_bfloat16 h; unsigned short u; } v;
    v.h = __float2bfloat16(a);
    return v.u;
}
__device__ __forceinline__ float bfbits_lo(unsigned int u) { return __uint_as_float(u << 16); }
__device__ __forceinline__ float bfbits_hi(unsigned int u) { return __uint_as_float(u & 0xffff0000u); }

// ---------------- zero cursor/deg ----------------
__global__ __launch_bounds__(256) void k_zero(int4* __restrict__ p) {
    int i = blockIdx.x * 256 + threadIdx.x;          // 25000 int4 = 100000 ints
    if (i < NN / 4) p[i] = make_int4(0, 0, 0, 0);
}

// ---------------- scan stage A: per-block sums ----------------
__global__ __launch_bounds__(1024) void k_scanA(const int* __restrict__ deg, int* __restrict__ bsum) {
    __shared__ int s[1024];
    int t = threadIdx.x, i = blockIdx.x * 1024 + t;
    s[t] = (i < NN) ? deg[i] : 0;
    __syncthreads();
    for (int off = 512; off > 0; off >>= 1) {
        if (t < off) s[t] += s[t + off];
        __syncthreads();
    }
    if (t == 0) bsum[blockIdx.x] = s[0];
}

// ---------------- scan stage C: bsum-scan (absorbs old scanB) + local scan ----------------
__global__ __launch_bounds__(1024) void k_scanC(const int* __restrict__ deg, const int* __restrict__ bsum,
                                                int* __restrict__ start, int* __restrict__ cursor) {
    __shared__ int s[1024];
    __shared__ int bs[128];
    int t = threadIdx.x, i = blockIdx.x * 1024 + t;
    if (t < 128) bs[t] = (t < SCAN_B) ? bsum[t] : 0;
    int d = (i < NN) ? deg[i] : 0;
    s[t] = d;
    __syncthreads();
    // inclusive scan of the 98 block sums (all threads hit the barriers)
    for (int off = 1; off < 128; off <<= 1) {
        int u = 0;
        if (t < 128 && t >= off) u = bs[t - off];
        __syncthreads();
        if (t < 128 && t >= off) bs[t] += u;
        __syncthreads();
    }
    // inclusive scan of this block's 1024 degrees
    for (int off = 1; off < 1024; off <<= 1) {
        int u = (t >= off) ? s[t - off] : 0;
        __syncthreads();
        s[t] += u;
        __syncthreads();
    }
    int base = (blockIdx.x == 0) ? 0 : bs[blockIdx.x - 1];
    if (i < NN) {
        int ex = base + s[t] - d;
        start[i] = ex;
        cursor[i] = ex;
    }
    if (blockIdx.x == SCAN_B - 1 && t == 0) start[NN] = bs[SCAN_B - 1];   // = NE
}

// ---------------- GEMM1 tile body (MFMA bf16): h1b = bf16(x @ W1) ----------------
// 128x64 tile, 256 threads (4 waves). LDS swizzled (verified rounds 2-4).
__device__ __forceinline__ void gemm1_tile(const float* __restrict__ x,
                                           const float* __restrict__ W1,
                                           unsigned short* __restrict__ h1b,
                                           int tile, int tid,
                                           unsigned short* xs, unsigned short* ws) {
    const int lane = tid & 63;
    const int wv   = tid >> 6;
    const int row0 = tile * 128;

    f32x4 acc[2][4];
#pragma unroll
    for (int i = 0; i < 2; ++i)
#pragma unroll
        for (int j = 0; j < 4; ++j) acc[i][j] = (f32x4){0.f, 0.f, 0.f, 0.f};

    for (int k0 = 0; k0 < NF; k0 += 64) {
#pragma unroll
        for (int p = 0; p < 4; ++p) {
            int u  = tid + p * 256;
            int r  = u >> 3, sl = u & 7;
            int gm = row0 + r, gk = k0 + sl * 8;
            float e[8];
            if (gm < NN && gk + 8 <= NF) {
                float4 va = *(const float4*)(x + (long)gm * NF + gk);
                float4 vb = *(const float4*)(x + (long)gm * NF + gk + 4);
                e[0]=va.x; e[1]=va.y; e[2]=va.z; e[3]=va.w;
                e[4]=vb.x; e[5]=vb.y; e[6]=vb.z; e[7]=vb.w;
            } else {
#pragma unroll
                for (int j = 0; j < 8; ++j)
                    e[j] = (gm < NN && gk + j < NF) ? x[(long)gm * NF + gk + j] : 0.f;
            }
            uint4 pk;
            pk.x = pkbf(e[0], e[1]);
            pk.y = pkbf(e[2], e[3]);
            pk.z = pkbf(e[4], e[5]);
            pk.w = pkbf(e[6], e[7]);
            *(uint4*)(xs + r * 64 + (sl ^ (r & 7)) * 8) = pk;
        }
#pragma unroll
        for (int p = 0; p < 2; ++p) {
            int u  = tid + p * 256;
            int n  = u & 63, sl = u >> 6;
            int gk = k0 + sl * 8;
            float e[8];
#pragma unroll
            for (int j = 0; j < 8; ++j)
                e[j] = (gk + j < NF) ? W1[(long)(gk + j) * NH + n] : 0.f;
            uint4 pk;
            pk.x = pkbf(e[0], e[1]);
            pk.y = pkbf(e[2], e[3]);
            pk.z = pkbf(e[4], e[5]);
            pk.w = pkbf(e[6], e[7]);
            *(uint4*)(ws + n * 64 + (sl ^ (n & 7)) * 8) = pk;
        }
        __syncthreads();
#pragma unroll
        for (int ks = 0; ks < 2; ++ks) {
            const int kg = ks * 4 + (lane >> 4);
            bf16x8 af[2], bfr[4];
#pragma unroll
            for (int i = 0; i < 2; ++i) {
                int r = wv * 32 + i * 16 + (lane & 15);
                af[i] = *(const bf16x8*)(xs + r * 64 + (kg ^ (r & 7)) * 8);
            }
#pragma unroll
            for (int j = 0; j < 4; ++j) {
                int n = j * 16 + (lane & 15);
                bfr[j] = *(const bf16x8*)(ws + n * 64 + (kg ^ (n & 7)) * 8);
            }
#pragma unroll
            for (int i = 0; i < 2; ++i)
#pragma unroll
                for (int j = 0; j < 4; ++j)
                    acc[i][j] = __builtin_amdgcn_mfma_f32_16x16x32_bf16(af[i], bfr[j], acc[i][j], 0, 0, 0);
        }
        __syncthreads();
    }
    // C/D: col = lane&15, row = (lane>>4)*4 + q ; store bf16
#pragma unroll
    for (int i = 0; i < 2; ++i) {
        int mbase = row0 + wv * 32 + i * 16 + (lane >> 4) * 4;
#pragma unroll
        for (int q = 0; q < 4; ++q) {
            int gm = mbase + q;
            if (gm < NN) {
#pragma unroll
                for (int j = 0; j < 4; ++j)
                    h1b[(long)gm * NH + j * 16 + (lane & 15)] = bf1(acc[i][j][q]);
            }
        }
    }
}

// ---------------- fused: gemm1 half A + degree histogram ----------------
__global__ __launch_bounds__(256) void k_g1a(const float* __restrict__ x, const float* __restrict__ W1,
                                             unsigned short* __restrict__ h1b,
                                             const int* __restrict__ dst, int* __restrict__ deg) {
    __shared__ unsigned short xs[128 * 64];
    __shared__ unsigned short ws[64 * 64];
    int bid = blockIdx.x, tid = threadIdx.x;
    if (bid >= G1HALF) {                       // hist role
        int rb = bid - G1HALF;
        for (int e = rb * 256 + tid; e < NE; e += ROLEB * 256)
            atomicAdd(&deg[dst[e]], 1);
        return;
    }
    gemm1_tile(x, W1, h1b, bid, tid, xs, ws);
}

// ---------------- fused: gemm1 half B + edge scatter ----------------
__global__ __launch_bounds__(256) void k_g1b(const float* __restrict__ x, const float* __restrict__ W1,
                                             unsigned short* __restrict__ h1b,
                                             const int* __restrict__ src, const int* __restrict__ dst,
                                             const float* __restrict__ ew,
                                             int* __restrict__ cursor, int2* __restrict__ edges) {
    __shared__ unsigned short xs[128 * 64];
    __shared__ unsigned short ws[64 * 64];
    int bid = blockIdx.x, tid = threadIdx.x;
    if (bid >= G1HALF) {                       // scatter role
        int rb = bid - G1HALF;
        for (int e = rb * 256 + tid; e < NE; e += ROLEB * 256) {
            int p = atomicAdd(&cursor[dst[e]], 1);
            edges[p] = make_int2(src[e], __float_as_int(ew[e]));
        }
        return;
    }
    gemm1_tile(x, W1, h1b, G1HALF + bid, tid, xs, ws);
}

// ---------------- SpMM1 + bias + ReLU: 8 edge-slots x 8 bf16x8-lanes ----------------
__global__ __launch_bounds__(256) void k_spmm1(const int* __restrict__ start,
                                               const int2* __restrict__ edges,
                                               const unsigned short* __restrict__ h1b,
                                               const float* __restrict__ b1,
                                               unsigned short* __restrict__ hb) {
    int wid  = (blockIdx.x * 256 + threadIdx.x) >> 6;
    int lane = threadIdx.x & 63;
    if (wid >= NN) return;
    int fo = lane & 7, es = lane >> 3;
    int s = start[wid], e = start[wid + 1];
    float a[8] = {0.f, 0.f, 0.f, 0.f, 0.f, 0.f, 0.f, 0.f};
    for (int p = s + es; p < e; p += 8) {
        int2 r = edges[p];
        float w = __int_as_float(r.y);
        const uint4 v = *(const uint4*)(h1b + (long)r.x * NH + fo * 8);
        a[0] += w * bfbits_lo(v.x); a[1] += w * bfbits_hi(v.x);
        a[2] += w * bfbits_lo(v.y); a[3] += w * bfbits_hi(v.y);
        a[4] += w * bfbits_lo(v.z); a[5] += w * bfbits_hi(v.z);
        a[6] += w * bfbits_lo(v.w); a[7] += w * bfbits_hi(v.w);
    }
#pragma unroll
    for (int m = 8; m <= 32; m <<= 1)
#pragma unroll
        for (int j = 0; j < 8; ++j) a[j] += __shfl_xor(a[j], m, 64);
    if (es == 0) {
        float4 ba = *(const float4*)(b1 + fo * 8);
        float4 bb = *(const float4*)(b1 + fo * 8 + 4);
        float r0 = fmaxf(a[0] + ba.x, 0.f), r1 = fmaxf(a[1] + ba.y, 0.f);
        float r2 = fmaxf(a[2] + ba.z, 0.f), r3 = fmaxf(a[3] + ba.w, 0.f);
        float r4 = fmaxf(a[4] + bb.x, 0.f), r5 = fmaxf(a[5] + bb.y, 0.f);
        float r6 = fmaxf(a[6] + bb.z, 0.f), r7 = fmaxf(a[7] + bb.w, 0.f);
        uint4 pk;
        pk.x = pkbf(r0, r1);
        pk.y = pkbf(r2, r3);
        pk.z = pkbf(r4, r5);
        pk.w = pkbf(r6, r7);
        *(uint4*)(hb + (long)wid * NH + fo * 8) = pk;
    }
}

// ---------------- GEMM2: h2b = bf16(h @ W2)  (bf16 h, fp32 accum) ----------------
__global__ __launch_bounds__(256) void k_gemm2(const unsigned short* __restrict__ hb,
                                               const float* __restrict__ W2,
                                               unsigned short* __restrict__ h2b) {
    __shared__ float hs[64][65];
    __shared__ float w2s[64 * 16];
    const int tid  = threadIdx.x;
    const int row0 = blockIdx.x * 64;
    for (int idx = tid; idx < 1024; idx += 256) w2s[idx] = W2[idx];
    for (int u = tid; u < 512; u += 256) {        // 64 rows x 8 chunks of 8 bf16
        int m = u >> 3, c = u & 7;
        int gm = row0 + m;
        uint4 v = make_uint4(0u, 0u, 0u, 0u);
        if (gm < NN) v = *(const uint4*)(hb + (long)gm * NH + c * 8);
        float* hrow = &hs[m][c * 8];
        hrow[0] = bfbits_lo(v.x); hrow[1] = bfbits_hi(v.x);
        hrow[2] = bfbits_lo(v.y); hrow[3] = bfbits_hi(v.y);
        hrow[4] = bfbits_lo(v.z); hrow[5] = bfbits_hi(v.z);
        hrow[6] = bfbits_lo(v.w); hrow[7] = bfbits_hi(v.w);
    }
    __syncthreads();
    const int pr = tid & 7;       // col pair -> cols 2pr, 2pr+1
    const int m2 = tid >> 3;      // rows 2*m2, 2*m2+1
    float a00 = 0.f, a01 = 0.f, a10 = 0.f, a11 = 0.f;
#pragma unroll 8
    for (int k = 0; k < 64; ++k) {
        float w0 = w2s[k * 16 + pr * 2], w1 = w2s[k * 16 + pr * 2 + 1];
        float h0 = hs[m2 * 2][k], h1 = hs[m2 * 2 + 1][k];
        a00 += h0 * w0; a01 += h0 * w1;
        a10 += h1 * w0; a11 += h1 * w1;
    }
    int gm0 = row0 + m2 * 2;
    if (gm0 < NN)     *(unsigned int*)(h2b + (long)gm0 * NC + pr * 2)       = pkbf(a00, a01);
    if (gm0 + 1 < NN) *(unsigned int*)(h2b + (long)(gm0 + 1) * NC + pr * 2) = pkbf(a10, a11);
}

// ---------------- SpMM2 + bias: 16 edge-slots x 4 bf16x4-features ----------------
__global__ __launch_bounds__(256) void k_spmm2(const int* __restrict__ start,
                                               const int2* __restrict__ edges,
                                               const unsigned short* __restrict__ h2b,
                                               const float* __restrict__ b2,
                                               float* __restrict__ out) {
    int wid  = (blockIdx.x * 256 + threadIdx.x) >> 6;
    int lane = threadIdx.x & 63;
    if (wid >= NN) return;
    int f4 = lane & 3, es = lane >> 2;
    int s = start[wid], e = start[wid + 1];
    float4 acc = make_float4(0.f, 0.f, 0.f, 0.f);
    for (int p = s + es; p < e; p += 16) {
        int2 r = edges[p];
        float wgt = __int_as_float(r.y);
        const uint2 v = *(const uint2*)(h2b + (long)r.x * NC + f4 * 4);
        acc.x += wgt * bfbits_lo(v.x); acc.y += wgt * bfbits_hi(v.x);
        acc.z += wgt * bfbits_lo(v.y); acc.w += wgt * bfbits_hi(v.y);
    }
#pragma unroll
    for (int m = 4; m <= 32; m <<= 1) {
        acc.x += __shfl_xor(acc.x, m, 64); acc.y += __shfl_xor(acc.y, m, 64);
        acc.z += __shfl_xor(acc.z, m, 64); acc.w += __shfl_xor(acc.w, m, 64);
    }
    if (es == 0) {
        const float4 b = *(const float4*)(b2 + f4 * 4);
        float4 r;
        r.x = acc.x + b.x; r.y = acc.y + b.y;
        r.z = acc.z + b.z; r.w = acc.w + b.w;
        *(float4*)(out + (long)wid * NC + f4 * 4) = r;
    }
}

extern "C" void kernel_launch(void* const* d_in, const int* in_sizes, int n_in,
                              void* d_out, int out_size, void* d_ws, size_t ws_size,
                              hipStream_t stream) {
    const float* x   = (const float*)d_in[0];
    const float* W1  = (const float*)d_in[1];
    const float* b1  = (const float*)d_in[2];
    const float* W2  = (const float*)d_in[3];
    const float* b2  = (const float*)d_in[4];
    const float* ew  = (const float*)d_in[5];
    const int*   src = (const int*)d_in[6];
    const int*   dst = (const int*)d_in[7];
    float* out = (float*)d_out;

    // workspace layout (<40 MB)
    char* w = (char*)d_ws;
    unsigned short* h1b = (unsigned short*)(w + 0);          // 12.8 MB bf16 x@W1
    unsigned short* hb  = (unsigned short*)(w + 12800000);   // 12.8 MB bf16 relu layer1
    unsigned short* h2b = (unsigned short*)(w + 25600000);   // 3.2 MB bf16 h@W2
    int*   bsum   = (int*) (w + 32000000);                   // 98 ints
    int*   startp = (int*) (w + 32001024);                   // 100001 ints
    int*   cursor = (int*) (w + 32402048);                   // 100000 ints (deg -> cursor)
    int2*  edges  = (int2*)(w + 32803072);                   // 6.4 MB (src, w) records

    k_zero <<<(NN / 4 + 255) / 256, 256, 0, stream>>>((int4*)cursor);
    k_g1a  <<<G1HALF + ROLEB, 256, 0, stream>>>(x, W1, h1b, dst, cursor);
    k_scanA<<<SCAN_B, 1024, 0, stream>>>(cursor, bsum);
    k_scanC<<<SCAN_B, 1024, 0, stream>>>(cursor, bsum, startp, cursor);
    k_g1b  <<<G1HALF + ROLEB, 256, 0, stream>>>(x, W1, h1b, src, dst, ew, cursor, edges);
    k_spmm1<<<(NN * 64) / 256, 256, 0, stream>>>(startp, edges, h1b, b1, hb);
    k_gemm2<<<(NN + 63) / 64, 256, 0, stream>>>(hb, W2, h2b);
    k_spmm2<<<(NN * 64) / 256, 256, 0, stream>>>(startp, edges, h2b, b2, out);
}

// Round 6
// 210.329 us; speedup vs baseline: 1.1146x; 1.1146x over previous
//
#include <hip/hip_runtime.h>

#define NN 100000   // nodes
#define NE 800000   // edges
#define NF 500      // in features
#define NH 64       // hidden
#define NC 16       // classes
#define SCAN_B 98   // 98 * 1024 >= NN
#define G1HALF 391
#define ROLEB 224   // extra hist/scatter blocks fused into gemm1 halves

typedef __attribute__((ext_vector_type(4))) float f32x4;
typedef __attribute__((ext_vector_type(8))) short bf16x8;  // 8 bf16 (4 VGPRs)

// raw RNE fp32->bf16 (proven rounds 2-4; ~4 VALU, no NaN-canonicalization branch)
__device__ __forceinline__ unsigned int f2bf(float f) {
    union { float f; unsigned int u; } v; v.f = f;
    return (v.u + 0x7FFFu + ((v.u >> 16) & 1u)) >> 16;   // RNE
}
__device__ __forceinline__ unsigned int pkbf(float a, float b) {
    return f2bf(a) | (f2bf(b) << 16);
}
__device__ __forceinline__ float bfbits_lo(unsigned int u) { return __uint_as_float(u << 16); }
__device__ __forceinline__ float bfbits_hi(unsigned int u) { return __uint_as_float(u & 0xffff0000u); }

// ---------------- zero cursor/deg ----------------
__global__ __launch_bounds__(256) void k_zero(int4* __restrict__ p) {
    int i = blockIdx.x * 256 + threadIdx.x;          // 25000 int4 = 100000 ints
    if (i < NN / 4) p[i] = make_int4(0, 0, 0, 0);
}

// ---------------- scan stage A: per-block sums ----------------
__global__ __launch_bounds__(1024) void k_scanA(const int* __restrict__ deg, int* __restrict__ bsum) {
    __shared__ int s[1024];
    int t = threadIdx.x, i = blockIdx.x * 1024 + t;
    s[t] = (i < NN) ? deg[i] : 0;
    __syncthreads();
    for (int off = 512; off > 0; off >>= 1) {
        if (t < off) s[t] += s[t + off];
        __syncthreads();
    }
    if (t == 0) bsum[blockIdx.x] = s[0];
}

// ---------------- scan stage C: bsum-scan (absorbed scanB) + local scan ----------------
__global__ __launch_bounds__(1024) void k_scanC(const int* __restrict__ deg, const int* __restrict__ bsum,
                                                int* __restrict__ start, int* __restrict__ cursor) {
    __shared__ int s[1024];
    __shared__ int bs[128];
    int t = threadIdx.x, i = blockIdx.x * 1024 + t;
    if (t < 128) bs[t] = (t < SCAN_B) ? bsum[t] : 0;
    int d = (i < NN) ? deg[i] : 0;
    s[t] = d;
    __syncthreads();
    // inclusive scan of the 98 block sums (all threads hit the barriers)
    for (int off = 1; off < 128; off <<= 1) {
        int u = 0;
        if (t < 128 && t >= off) u = bs[t - off];
        __syncthreads();
        if (t < 128 && t >= off) bs[t] += u;
        __syncthreads();
    }
    // inclusive scan of this block's 1024 degrees
    for (int off = 1; off < 1024; off <<= 1) {
        int u = (t >= off) ? s[t - off] : 0;
        __syncthreads();
        s[t] += u;
        __syncthreads();
    }
    int base = (blockIdx.x == 0) ? 0 : bs[blockIdx.x - 1];
    if (i < NN) {
        int ex = base + s[t] - d;
        start[i] = ex;
        cursor[i] = ex;
    }
    if (blockIdx.x == SCAN_B - 1 && t == 0) start[NN] = bs[SCAN_B - 1];   // = NE
}

// ---------------- GEMM1 tile body (MFMA bf16): h1b = bf16(x @ W1) ----------------
// 128x64 tile, 256 threads (4 waves). LDS swizzled (verified rounds 2-5).
__device__ __forceinline__ void gemm1_tile(const float* __restrict__ x,
                                           const float* __restrict__ W1,
                                           unsigned short* __restrict__ h1b,
                                           int tile, int tid,
                                           unsigned short* xs, unsigned short* ws) {
    const int lane = tid & 63;
    const int wv   = tid >> 6;
    const int row0 = tile * 128;

    f32x4 acc[2][4];
#pragma unroll
    for (int i = 0; i < 2; ++i)
#pragma unroll
        for (int j = 0; j < 4; ++j) acc[i][j] = (f32x4){0.f, 0.f, 0.f, 0.f};

    for (int k0 = 0; k0 < NF; k0 += 64) {
#pragma unroll
        for (int p = 0; p < 4; ++p) {
            int u  = tid + p * 256;
            int r  = u >> 3, sl = u & 7;
            int gm = row0 + r, gk = k0 + sl * 8;
            float e[8];
            if (gm < NN && gk + 8 <= NF) {
                float4 va = *(const float4*)(x + (long)gm * NF + gk);
                float4 vb = *(const float4*)(x + (long)gm * NF + gk + 4);
                e[0]=va.x; e[1]=va.y; e[2]=va.z; e[3]=va.w;
                e[4]=vb.x; e[5]=vb.y; e[6]=vb.z; e[7]=vb.w;
            } else {
#pragma unroll
                for (int j = 0; j < 8; ++j)
                    e[j] = (gm < NN && gk + j < NF) ? x[(long)gm * NF + gk + j] : 0.f;
            }
            uint4 pk;
            pk.x = pkbf(e[0], e[1]);
            pk.y = pkbf(e[2], e[3]);
            pk.z = pkbf(e[4], e[5]);
            pk.w = pkbf(e[6], e[7]);
            *(uint4*)(xs + r * 64 + (sl ^ (r & 7)) * 8) = pk;
        }
#pragma unroll
        for (int p = 0; p < 2; ++p) {
            int u  = tid + p * 256;
            int n  = u & 63, sl = u >> 6;
            int gk = k0 + sl * 8;
            float e[8];
#pragma unroll
            for (int j = 0; j < 8; ++j)
                e[j] = (gk + j < NF) ? W1[(long)(gk + j) * NH + n] : 0.f;
            uint4 pk;
            pk.x = pkbf(e[0], e[1]);
            pk.y = pkbf(e[2], e[3]);
            pk.z = pkbf(e[4], e[5]);
            pk.w = pkbf(e[6], e[7]);
            *(uint4*)(ws + n * 64 + (sl ^ (n & 7)) * 8) = pk;
        }
        __syncthreads();
#pragma unroll
        for (int ks = 0; ks < 2; ++ks) {
            const int kg = ks * 4 + (lane >> 4);
            bf16x8 af[2], bfr[4];
#pragma unroll
            for (int i = 0; i < 2; ++i) {
                int r = wv * 32 + i * 16 + (lane & 15);
                af[i] = *(const bf16x8*)(xs + r * 64 + (kg ^ (r & 7)) * 8);
            }
#pragma unroll
            for (int j = 0; j < 4; ++j) {
                int n = j * 16 + (lane & 15);
                bfr[j] = *(const bf16x8*)(ws + n * 64 + (kg ^ (n & 7)) * 8);
            }
#pragma unroll
            for (int i = 0; i < 2; ++i)
#pragma unroll
                for (int j = 0; j < 4; ++j)
                    acc[i][j] = __builtin_amdgcn_mfma_f32_16x16x32_bf16(af[i], bfr[j], acc[i][j], 0, 0, 0);
        }
        __syncthreads();
    }
    // C/D: col = lane&15, row = (lane>>4)*4 + q ; store bf16
#pragma unroll
    for (int i = 0; i < 2; ++i) {
        int mbase = row0 + wv * 32 + i * 16 + (lane >> 4) * 4;
#pragma unroll
        for (int q = 0; q < 4; ++q) {
            int gm = mbase + q;
            if (gm < NN) {
#pragma unroll
                for (int j = 0; j < 4; ++j)
                    h1b[(long)gm * NH + j * 16 + (lane & 15)] = (unsigned short)f2bf(acc[i][j][q]);
            }
        }
    }
}

// ---------------- fused: gemm1 half A + degree histogram ----------------
__global__ __launch_bounds__(256) void k_g1a(const float* __restrict__ x, const float* __restrict__ W1,
                                             unsigned short* __restrict__ h1b,
                                             const int* __restrict__ dst, int* __restrict__ deg) {
    __shared__ unsigned short xs[128 * 64];
    __shared__ unsigned short ws[64 * 64];
    int bid = blockIdx.x, tid = threadIdx.x;
    if (bid >= G1HALF) {                       // hist role
        int rb = bid - G1HALF;
        for (int e = rb * 256 + tid; e < NE; e += ROLEB * 256)
            atomicAdd(&deg[dst[e]], 1);
        return;
    }
    gemm1_tile(x, W1, h1b, bid, tid, xs, ws);
}

// ---------------- fused: gemm1 half B + edge scatter ----------------
__global__ __launch_bounds__(256) void k_g1b(const float* __restrict__ x, const float* __restrict__ W1,
                                             unsigned short* __restrict__ h1b,
                                             const int* __restrict__ src, const int* __restrict__ dst,
                                             const float* __restrict__ ew,
                                             int* __restrict__ cursor, int2* __restrict__ edges) {
    __shared__ unsigned short xs[128 * 64];
    __shared__ unsigned short ws[64 * 64];
    int bid = blockIdx.x, tid = threadIdx.x;
    if (bid >= G1HALF) {                       // scatter role
        int rb = bid - G1HALF;
        for (int e = rb * 256 + tid; e < NE; e += ROLEB * 256) {
            int p = atomicAdd(&cursor[dst[e]], 1);
            edges[p] = make_int2(src[e], __float_as_int(ew[e]));
        }
        return;
    }
    gemm1_tile(x, W1, h1b, G1HALF + bid, tid, xs, ws);
}

// ---------------- SpMM1 + bias + ReLU: 8 edge-slots x 8 bf16x8-lanes ----------------
__global__ __launch_bounds__(256) void k_spmm1(const int* __restrict__ start,
                                               const int2* __restrict__ edges,
                                               const unsigned short* __restrict__ h1b,
                                               const float* __restrict__ b1,
                                               unsigned short* __restrict__ hb) {
    int wid  = (blockIdx.x * 256 + threadIdx.x) >> 6;
    int lane = threadIdx.x & 63;
    if (wid >= NN) return;
    int fo = lane & 7, es = lane >> 3;
    int s = start[wid], e = start[wid + 1];
    float a[8] = {0.f, 0.f, 0.f, 0.f, 0.f, 0.f, 0.f, 0.f};
    for (int p = s + es; p < e; p += 8) {
        int2 r = edges[p];
        float w = __int_as_float(r.y);
        const uint4 v = *(const uint4*)(h1b + (long)r.x * NH + fo * 8);
        a[0] += w * bfbits_lo(v.x); a[1] += w * bfbits_hi(v.x);
        a[2] += w * bfbits_lo(v.y); a[3] += w * bfbits_hi(v.y);
        a[4] += w * bfbits_lo(v.z); a[5] += w * bfbits_hi(v.z);
        a[6] += w * bfbits_lo(v.w); a[7] += w * bfbits_hi(v.w);
    }
#pragma unroll
    for (int m = 8; m <= 32; m <<= 1)
#pragma unroll
        for (int j = 0; j < 8; ++j) a[j] += __shfl_xor(a[j], m, 64);
    if (es == 0) {
        float4 ba = *(const float4*)(b1 + fo * 8);
        float4 bb = *(const float4*)(b1 + fo * 8 + 4);
        float r0 = fmaxf(a[0] + ba.x, 0.f), r1 = fmaxf(a[1] + ba.y, 0.f);
        float r2 = fmaxf(a[2] + ba.z, 0.f), r3 = fmaxf(a[3] + ba.w, 0.f);
        float r4 = fmaxf(a[4] + bb.x, 0.f), r5 = fmaxf(a[5] + bb.y, 0.f);
        float r6 = fmaxf(a[6] + bb.z, 0.f), r7 = fmaxf(a[7] + bb.w, 0.f);
        uint4 pk;
        pk.x = pkbf(r0, r1);
        pk.y = pkbf(r2, r3);
        pk.z = pkbf(r4, r5);
        pk.w = pkbf(r6, r7);
        *(uint4*)(hb + (long)wid * NH + fo * 8) = pk;
    }
}

// ---------------- GEMM2: h2b = bf16(h @ W2)  (bf16 h, fp32 accum) ----------------
__global__ __launch_bounds__(256) void k_gemm2(const unsigned short* __restrict__ hb,
                                               const float* __restrict__ W2,
                                               unsigned short* __restrict__ h2b) {
    __shared__ float hs[64][65];
    __shared__ float w2s[64 * 16];
    const int tid  = threadIdx.x;
    const int row0 = blockIdx.x * 64;
    for (int idx = tid; idx < 1024; idx += 256) w2s[idx] = W2[idx];
    for (int u = tid; u < 512; u += 256) {        // 64 rows x 8 chunks of 8 bf16
        int m = u >> 3, c = u & 7;
        int gm = row0 + m;
        uint4 v = make_uint4(0u, 0u, 0u, 0u);
        if (gm < NN) v = *(const uint4*)(hb + (long)gm * NH + c * 8);
        float* hrow = &hs[m][c * 8];
        hrow[0] = bfbits_lo(v.x); hrow[1] = bfbits_hi(v.x);
        hrow[2] = bfbits_lo(v.y); hrow[3] = bfbits_hi(v.y);
        hrow[4] = bfbits_lo(v.z); hrow[5] = bfbits_hi(v.z);
        hrow[6] = bfbits_lo(v.w); hrow[7] = bfbits_hi(v.w);
    }
    __syncthreads();
    const int pr = tid & 7;       // col pair -> cols 2pr, 2pr+1
    const int m2 = tid >> 3;      // rows 2*m2, 2*m2+1
    float a00 = 0.f, a01 = 0.f, a10 = 0.f, a11 = 0.f;
#pragma unroll 8
    for (int k = 0; k < 64; ++k) {
        float w0 = w2s[k * 16 + pr * 2], w1 = w2s[k * 16 + pr * 2 + 1];
        float h0 = hs[m2 * 2][k], h1 = hs[m2 * 2 + 1][k];
        a00 += h0 * w0; a01 += h0 * w1;
        a10 += h1 * w0; a11 += h1 * w1;
    }
    int gm0 = row0 + m2 * 2;
    if (gm0 < NN)     *(unsigned int*)(h2b + (long)gm0 * NC + pr * 2)       = pkbf(a00, a01);
    if (gm0 + 1 < NN) *(unsigned int*)(h2b + (long)(gm0 + 1) * NC + pr * 2) = pkbf(a10, a11);
}

// ---------------- SpMM2 + bias: 16 edge-slots x 4 bf16x4-features ----------------
__global__ __launch_bounds__(256) void k_spmm2(const int* __restrict__ start,
                                               const int2* __restrict__ edges,
                                               const unsigned short* __restrict__ h2b,
                                               const float* __restrict__ b2,
                                               float* __restrict__ out) {
    int wid  = (blockIdx.x * 256 + threadIdx.x) >> 6;
    int lane = threadIdx.x & 63;
    if (wid >= NN) return;
    int f4 = lane & 3, es = lane >> 2;
    int s = start[wid], e = start[wid + 1];
    float4 acc = make_float4(0.f, 0.f, 0.f, 0.f);
    for (int p = s + es; p < e; p += 16) {
        int2 r = edges[p];
        float wgt = __int_as_float(r.y);
        const uint2 v = *(const uint2*)(h2b + (long)r.x * NC + f4 * 4);
        acc.x += wgt * bfbits_lo(v.x); acc.y += wgt * bfbits_hi(v.x);
        acc.z += wgt * bfbits_lo(v.y); acc.w += wgt * bfbits_hi(v.y);
    }
#pragma unroll
    for (int m = 4; m <= 32; m <<= 1) {
        acc.x += __shfl_xor(acc.x, m, 64); acc.y += __shfl_xor(acc.y, m, 64);
        acc.z += __shfl_xor(acc.z, m, 64); acc.w += __shfl_xor(acc.w, m, 64);
    }
    if (es == 0) {
        const float4 b = *(const float4*)(b2 + f4 * 4);
        float4 r;
        r.x = acc.x + b.x; r.y = acc.y + b.y;
        r.z = acc.z + b.z; r.w = acc.w + b.w;
        *(float4*)(out + (long)wid * NC + f4 * 4) = r;
    }
}

extern "C" void kernel_launch(void* const* d_in, const int* in_sizes, int n_in,
                              void* d_out, int out_size, void* d_ws, size_t ws_size,
                              hipStream_t stream) {
    const float* x   = (const float*)d_in[0];
    const float* W1  = (const float*)d_in[1];
    const float* b1  = (const float*)d_in[2];
    const float* W2  = (const float*)d_in[3];
    const float* b2  = (const float*)d_in[4];
    const float* ew  = (const float*)d_in[5];
    const int*   src = (const int*)d_in[6];
    const int*   dst = (const int*)d_in[7];
    float* out = (float*)d_out;

    // workspace layout (<40 MB)
    char* w = (char*)d_ws;
    unsigned short* h1b = (unsigned short*)(w + 0);          // 12.8 MB bf16 x@W1
    unsigned short* hb  = (unsigned short*)(w + 12800000);   // 12.8 MB bf16 relu layer1
    unsigned short* h2b = (unsigned short*)(w + 25600000);   // 3.2 MB bf16 h@W2
    int*   bsum   = (int*) (w + 32000000);                   // 98 ints
    int*   startp = (int*) (w + 32001024);                   // 100001 ints
    int*   cursor = (int*) (w + 32402048);                   // 100000 ints (deg -> cursor)
    int2*  edges  = (int2*)(w + 32803072);                   // 6.4 MB (src, w) records

    k_zero <<<(NN / 4 + 255) / 256, 256, 0, stream>>>((int4*)cursor);
    k_g1a  <<<G1HALF + ROLEB, 256, 0, stream>>>(x, W1, h1b, dst, cursor);
    k_scanA<<<SCAN_B, 1024, 0, stream>>>(cursor, bsum);
    k_scanC<<<SCAN_B, 1024, 0, stream>>>(cursor, bsum, startp, cursor);
    k_g1b  <<<G1HALF + ROLEB, 256, 0, stream>>>(x, W1, h1b, src, dst, ew, cursor, edges);
    k_spmm1<<<(NN * 64) / 256, 256, 0, stream>>>(startp, edges, h1b, b1, hb);
    k_gemm2<<<(NN + 63) / 64, 256, 0, stream>>>(hb, W2, h2b);
    k_spmm2<<<(NN * 64) / 256, 256, 0, stream>>>(startp, edges, h2b, b2, out);
}

// Round 8
// 196.157 us; speedup vs baseline: 1.1951x; 1.0723x over previous
//
#include <hip/hip_runtime.h>

#define NN 100000   // nodes
#define NE 800000   // edges
#define NF 500      // in features
#define NH 64       // hidden
#define NC 16       // classes
#define SCAN_B 98   // 98 * 1024 >= NN
#define G1TILES 782 // ceil(100000/128)
#define ROLEB 224   // hist role blocks fused into k_g1

typedef __attribute__((ext_vector_type(4))) float f32x4;
typedef __attribute__((ext_vector_type(8))) short bf16x8;  // 8 bf16 (4 VGPRs)

// raw RNE fp32->bf16 (proven; ~4 VALU, no NaN-canonicalization branch)
__device__ __forceinline__ unsigned int f2bf(float f) {
    union { float f; unsigned int u; } v; v.f = f;
    return (v.u + 0x7FFFu + ((v.u >> 16) & 1u)) >> 16;   // RNE
}
__device__ __forceinline__ unsigned int pkbf(float a, float b) {
    return f2bf(a) | (f2bf(b) << 16);
}
__device__ __forceinline__ float bfbits_lo(unsigned int u) { return __uint_as_float(u << 16); }
__device__ __forceinline__ float bfbits_hi(unsigned int u) { return __uint_as_float(u & 0xffff0000u); }

// async HBM->LDS, 16B per lane; LDS dest = wave-uniform base + lane*16 (linear)
#define GLOAD_LDS16(g, l) __builtin_amdgcn_global_load_lds(                      \
    (const __attribute__((address_space(1))) void*)(g),                          \
    (__attribute__((address_space(3))) void*)(l), 16, 0, 0)

// ---------------- zero cursor/deg ----------------
__global__ __launch_bounds__(256) void k_zero(int4* __restrict__ p) {
    int i = blockIdx.x * 256 + threadIdx.x;          // 25000 int4 = 100000 ints
    if (i < NN / 4) p[i] = make_int4(0, 0, 0, 0);
}

// ---------------- scan stage A: per-block sums ----------------
__global__ __launch_bounds__(1024) void k_scanA(const int* __restrict__ deg, int* __restrict__ bsum) {
    __shared__ int s[1024];
    int t = threadIdx.x, i = blockIdx.x * 1024 + t;
    s[t] = (i < NN) ? deg[i] : 0;
    __syncthreads();
    for (int off = 512; off > 0; off >>= 1) {
        if (t < off) s[t] += s[t + off];
        __syncthreads();
    }
    if (t == 0) bsum[blockIdx.x] = s[0];
}

// ---------------- scan stage C: bsum-scan + local scan ----------------
__global__ __launch_bounds__(1024) void k_scanC(const int* __restrict__ deg, const int* __restrict__ bsum,
                                                int* __restrict__ start, int* __restrict__ cursor) {
    __shared__ int s[1024];
    __shared__ int bs[128];
    int t = threadIdx.x, i = blockIdx.x * 1024 + t;
    if (t < 128) bs[t] = (t < SCAN_B) ? bsum[t] : 0;
    int d = (i < NN) ? deg[i] : 0;
    s[t] = d;
    __syncthreads();
    for (int off = 1; off < 128; off <<= 1) {
        int u = 0;
        if (t < 128 && t >= off) u = bs[t - off];
        __syncthreads();
        if (t < 128 && t >= off) bs[t] += u;
        __syncthreads();
    }
    for (int off = 1; off < 1024; off <<= 1) {
        int u = (t >= off) ? s[t - off] : 0;
        __syncthreads();
        s[t] += u;
        __syncthreads();
    }
    int base = (blockIdx.x == 0) ? 0 : bs[blockIdx.x - 1];
    if (i < NN) {
        int ex = base + s[t] - d;
        start[i] = ex;
        cursor[i] = ex;
    }
    if (blockIdx.x == SCAN_B - 1 && t == 0) start[NN] = bs[SCAN_B - 1];   // = NE
}

// ---------------- scatter edges into CSR order ----------------
__global__ void k_scatter(const int* __restrict__ src, const int* __restrict__ dst,
                          const float* __restrict__ ew, int* __restrict__ cursor,
                          int2* __restrict__ edges) {
    int e = blockIdx.x * 256 + threadIdx.x;
    if (e < NE) {
        int p = atomicAdd(&cursor[dst[e]], 1);
        edges[p] = make_int2(src[e], __float_as_int(ew[e]));
    }
}

// ---------------- GEMM1 (full, MFMA bf16) + fused hist role ----------------
// 128x64 tile, 256 threads (4 waves). x staged fp32 via global_load_lds with
// pre-swizzled SOURCE addresses (LDS dest linear); converted to bf16 at
// fragment-load. W1 staged bf16, XOR-swizzled (proven layout).
__global__ __launch_bounds__(256) void k_g1(const float* __restrict__ x,
                                            const float* __restrict__ W1,
                                            unsigned short* __restrict__ h1b,
                                            const int* __restrict__ dst, int* __restrict__ deg) {
    __shared__ float xs[128 * 64];           // 32 KB fp32
    __shared__ unsigned short ws[64 * 64];   // 8 KB bf16
    const int bid = blockIdx.x, tid = threadIdx.x;
    if (bid >= G1TILES) {                    // hist role
        int rb = bid - G1TILES;
        for (int e = rb * 256 + tid; e < NE; e += ROLEB * 256)
            atomicAdd(&deg[dst[e]], 1);
        return;
    }
    const int lane = tid & 63;
    const int wv   = tid >> 6;
    const int row0 = bid * 128;

    f32x4 acc[2][4];
#pragma unroll
    for (int i = 0; i < 2; ++i)
#pragma unroll
        for (int j = 0; j < 4; ++j) acc[i][j] = (f32x4){0.f, 0.f, 0.f, 0.f};

    // per-lane pieces of the source swizzle (issue covers 4 rows x 64 floats)
    const int lr    = lane >> 4;         // row within issue group (0..3)
    const int lsl   = (lane & 15) >> 1;  // 8-float slot (0..7)
    const int lhalf = lane & 1;          // half-slot (0..1)
    const long maxidx = (long)NN * NF - 4;

    for (int kt = 0; kt < 8; ++kt) {
        const int k0 = kt * 64;
        // ---- x tile: 8 async issues/wave, source-swizzled, LDS linear ----
#pragma unroll
        for (int i = 0; i < 8; ++i) {
            int r  = wv * 32 + i * 4 + lr;
            int gm = row0 + r; if (gm >= NN) gm = NN - 1;   // pad rows: finite garbage, discarded at write
            long gi = (long)gm * NF + k0 + ((lsl ^ (r & 7)) << 3) + (lhalf << 2);
            if (gi > maxidx) gi = maxidx;                    // clamp: stay in-bounds (values killed by W=0)
            GLOAD_LDS16(x + gi, xs + (wv * 32 + i * 4) * 64);
        }
        // ---- W1 tile: bf16 pack, XOR-swizzled ----
#pragma unroll
        for (int p = 0; p < 2; ++p) {
            int u  = tid + p * 256;
            int n  = u & 63, sl = u >> 6;
            int gk = k0 + sl * 8;
            float e[8];
#pragma unroll
            for (int j = 0; j < 8; ++j)
                e[j] = (gk + j < NF) ? W1[(long)(gk + j) * NH + n] : 0.f;
            uint4 pk;
            pk.x = pkbf(e[0], e[1]);
            pk.y = pkbf(e[2], e[3]);
            pk.z = pkbf(e[4], e[5]);
            pk.w = pkbf(e[6], e[7]);
            *(uint4*)(ws + n * 64 + (sl ^ (n & 7)) * 8) = pk;
        }
        __syncthreads();   // drains vmcnt (gload_lds) + lgkm before use
        // ---- MFMA ----
#pragma unroll
        for (int ks = 0; ks < 2; ++ks) {
            const int kg = ks * 4 + (lane >> 4);
            bf16x8 af[2], bfr[4];
#pragma unroll
            for (int i = 0; i < 2; ++i) {
                int r = wv * 32 + i * 16 + (lane & 15);
                const float* srcp = xs + r * 64 + ((kg ^ (r & 7)) << 3);
                f32x4 lo = *(const f32x4*)(srcp);
                f32x4 hi = *(const f32x4*)(srcp + 4);
                uint4 pk;
                pk.x = pkbf(lo[0], lo[1]);
                pk.y = pkbf(lo[2], lo[3]);
                pk.z = pkbf(hi[0], hi[1]);
                pk.w = pkbf(hi[2], hi[3]);
                af[i] = *(bf16x8*)&pk;
            }
#pragma unroll
            for (int j = 0; j < 4; ++j) {
                int n = j * 16 + (lane & 15);
                bfr[j] = *(const bf16x8*)(ws + n * 64 + (kg ^ (n & 7)) * 8);
            }
#pragma unroll
            for (int i = 0; i < 2; ++i)
#pragma unroll
                for (int j = 0; j < 4; ++j)
                    acc[i][j] = __builtin_amdgcn_mfma_f32_16x16x32_bf16(af[i], bfr[j], acc[i][j], 0, 0, 0);
        }
        __syncthreads();
    }
    // C/D: col = lane&15, row = (lane>>4)*4 + q ; store bf16
#pragma unroll
    for (int i = 0; i < 2; ++i) {
        int mbase = row0 + wv * 32 + i * 16 + (lane >> 4) * 4;
#pragma unroll
        for (int q = 0; q < 4; ++q) {
            int gm = mbase + q;
            if (gm < NN) {
#pragma unroll
                for (int j = 0; j < 4; ++j)
                    h1b[(long)gm * NH + j * 16 + (lane & 15)] = (unsigned short)f2bf(acc[i][j][q]);
            }
        }
    }
}

// ---------------- SpMM1 + bias + ReLU: 8 edge-slots x 8 bf16x8-lanes ----------------
__global__ __launch_bounds__(256) void k_spmm1(const int* __restrict__ start,
                                               const int2* __restrict__ edges,
                                               const unsigned short* __restrict__ h1b,
                                               const float* __restrict__ b1,
                                               unsigned short* __restrict__ hb) {
    int wid  = (blockIdx.x * 256 + threadIdx.x) >> 6;
    int lane = threadIdx.x & 63;
    if (wid >= NN) return;
    int fo = lane & 7, es = lane >> 3;
    int s = start[wid], e = start[wid + 1];
    float a[8] = {0.f, 0.f, 0.f, 0.f, 0.f, 0.f, 0.f, 0.f};
    for (int p = s + es; p < e; p += 8) {
        int2 r = edges[p];
        float w = __int_as_float(r.y);
        const uint4 v = *(const uint4*)(h1b + (long)r.x * NH + fo * 8);
        a[0] += w * bfbits_lo(v.x); a[1] += w * bfbits_hi(v.x);
        a[2] += w * bfbits_lo(v.y); a[3] += w * bfbits_hi(v.y);
        a[4] += w * bfbits_lo(v.z); a[5] += w * bfbits_hi(v.z);
        a[6] += w * bfbits_lo(v.w); a[7] += w * bfbits_hi(v.w);
    }
#pragma unroll
    for (int m = 8; m <= 32; m <<= 1)
#pragma unroll
        for (int j = 0; j < 8; ++j) a[j] += __shfl_xor(a[j], m, 64);
    if (es == 0) {
        float4 ba = *(const float4*)(b1 + fo * 8);
        float4 bb = *(const float4*)(b1 + fo * 8 + 4);
        float r0 = fmaxf(a[0] + ba.x, 0.f), r1 = fmaxf(a[1] + ba.y, 0.f);
        float r2 = fmaxf(a[2] + ba.z, 0.f), r3 = fmaxf(a[3] + ba.w, 0.f);
        float r4 = fmaxf(a[4] + bb.x, 0.f), r5 = fmaxf(a[5] + bb.y, 0.f);
        float r6 = fmaxf(a[6] + bb.z, 0.f), r7 = fmaxf(a[7] + bb.w, 0.f);
        uint4 pk;
        pk.x = pkbf(r0, r1);
        pk.y = pkbf(r2, r3);
        pk.z = pkbf(r4, r5);
        pk.w = pkbf(r6, r7);
        *(uint4*)(hb + (long)wid * NH + fo * 8) = pk;
    }
}

// ---------------- GEMM2: h2b = bf16(h @ W2)  (bf16 h, fp32 accum) ----------------
__global__ __launch_bounds__(256) void k_gemm2(const unsigned short* __restrict__ hb,
                                               const float* __restrict__ W2,
                                               unsigned short* __restrict__ h2b) {
    __shared__ float hs[64][65];
    __shared__ float w2s[64 * 16];
    const int tid  = threadIdx.x;
    const int row0 = blockIdx.x * 64;
    for (int idx = tid; idx < 1024; idx += 256) w2s[idx] = W2[idx];
    for (int u = tid; u < 512; u += 256) {        // 64 rows x 8 chunks of 8 bf16
        int m = u >> 3, c = u & 7;
        int gm = row0 + m;
        uint4 v = make_uint4(0u, 0u, 0u, 0u);
        if (gm < NN) v = *(const uint4*)(hb + (long)gm * NH + c * 8);
        float* hrow = &hs[m][c * 8];
        hrow[0] = bfbits_lo(v.x); hrow[1] = bfbits_hi(v.x);
        hrow[2] = bfbits_lo(v.y); hrow[3] = bfbits_hi(v.y);
        hrow[4] = bfbits_lo(v.z); hrow[5] = bfbits_hi(v.z);
        hrow[6] = bfbits_lo(v.w); hrow[7] = bfbits_hi(v.w);
    }
    __syncthreads();
    const int pr = tid & 7;       // col pair -> cols 2pr, 2pr+1
    const int m2 = tid >> 3;      // rows 2*m2, 2*m2+1
    float a00 = 0.f, a01 = 0.f, a10 = 0.f, a11 = 0.f;
#pragma unroll 8
    for (int k = 0; k < 64; ++k) {
        float w0 = w2s[k * 16 + pr * 2], w1 = w2s[k * 16 + pr * 2 + 1];
        float h0 = hs[m2 * 2][k], h1 = hs[m2 * 2 + 1][k];
        a00 += h0 * w0; a01 += h0 * w1;
        a10 += h1 * w0; a11 += h1 * w1;
    }
    int gm0 = row0 + m2 * 2;
    if (gm0 < NN)     *(unsigned int*)(h2b + (long)gm0 * NC + pr * 2)       = pkbf(a00, a01);
    if (gm0 + 1 < NN) *(unsigned int*)(h2b + (long)(gm0 + 1) * NC + pr * 2) = pkbf(a10, a11);
}

// ---------------- SpMM2 + bias: 16 edge-slots x 4 bf16x4-features ----------------
__global__ __launch_bounds__(256) void k_spmm2(const int* __restrict__ start,
                                               const int2* __restrict__ edges,
                                               const unsigned short* __restrict__ h2b,
                                               const float* __restrict__ b2,
                                               float* __restrict__ out) {
    int wid  = (blockIdx.x * 256 + threadIdx.x) >> 6;
    int lane = threadIdx.x & 63;
    if (wid >= NN) return;
    int f4 = lane & 3, es = lane >> 2;
    int s = start[wid], e = start[wid + 1];
    float4 acc = make_float4(0.f, 0.f, 0.f, 0.f);
    for (int p = s + es; p < e; p += 16) {
        int2 r = edges[p];
        float wgt = __int_as_float(r.y);
        const uint2 v = *(const uint2*)(h2b + (long)r.x * NC + f4 * 4);
        acc.x += wgt * bfbits_lo(v.x); acc.y += wgt * bfbits_hi(v.x);
        acc.z += wgt * bfbits_lo(v.y); acc.w += wgt * bfbits_hi(v.y);
    }
#pragma unroll
    for (int m = 4; m <= 32; m <<= 1) {
        acc.x += __shfl_xor(acc.x, m, 64); acc.y += __shfl_xor(acc.y, m, 64);
        acc.z += __shfl_xor(acc.z, m, 64); acc.w += __shfl_xor(acc.w, m, 64);
    }
    if (es == 0) {
        const float4 b = *(const float4*)(b2 + f4 * 4);
        float4 r;
        r.x = acc.x + b.x; r.y = acc.y + b.y;
        r.z = acc.z + b.z; r.w = acc.w + b.w;
        *(float4*)(out + (long)wid * NC + f4 * 4) = r;
    }
}

extern "C" void kernel_launch(void* const* d_in, const int* in_sizes, int n_in,
                              void* d_out, int out_size, void* d_ws, size_t ws_size,
                              hipStream_t stream) {
    const float* x   = (const float*)d_in[0];
    const float* W1  = (const float*)d_in[1];
    const float* b1  = (const float*)d_in[2];
    const float* W2  = (const float*)d_in[3];
    const float* b2  = (const float*)d_in[4];
    const float* ew  = (const float*)d_in[5];
    const int*   src = (const int*)d_in[6];
    const int*   dst = (const int*)d_in[7];
    float* out = (float*)d_out;

    // workspace layout (<40 MB)
    char* w = (char*)d_ws;
    unsigned short* h1b = (unsigned short*)(w + 0);          // 12.8 MB bf16 x@W1
    unsigned short* hb  = (unsigned short*)(w + 12800000);   // 12.8 MB bf16 relu layer1
    unsigned short* h2b = (unsigned short*)(w + 25600000);   // 3.2 MB bf16 h@W2
    int*   bsum   = (int*) (w + 32000000);                   // 98 ints
    int*   startp = (int*) (w + 32001024);                   // 100001 ints
    int*   cursor = (int*) (w + 32402048);                   // 100000 ints (deg -> cursor)
    int2*  edges  = (int2*)(w + 32803072);                   // 6.4 MB (src, w) records

    k_zero   <<<(NN / 4 + 255) / 256, 256, 0, stream>>>((int4*)cursor);
    k_g1     <<<G1TILES + ROLEB, 256, 0, stream>>>(x, W1, h1b, dst, cursor);
    k_scanA  <<<SCAN_B, 1024, 0, stream>>>(cursor, bsum);
    k_scanC  <<<SCAN_B, 1024, 0, stream>>>(cursor, bsum, startp, cursor);
    k_scatter<<<(NE + 255) / 256, 256, 0, stream>>>(src, dst, ew, cursor, edges);
    k_spmm1  <<<(NN * 64) / 256, 256, 0, stream>>>(startp, edges, h1b, b1, hb);
    k_gemm2  <<<(NN + 63) / 64, 256, 0, stream>>>(hb, W2, h2b);
    k_spmm2  <<<(NN * 64) / 256, 256, 0, stream>>>(startp, edges, h2b, b2, out);
}